// Round 6
// baseline (2717.311 us; speedup 1.0000x reference)
//
#include <hip/hip_runtime.h>
#include <math.h>

#define B_N   2
#define S_N   20197
#define M_N   (B_N * S_N)   // 40394 rows
#define D_N   256
#define NH_N  8
#define HD_N  32
#define DFF_N 1024

typedef __attribute__((ext_vector_type(8))) short short8;
typedef __attribute__((ext_vector_type(4))) float f32x4;

__device__ __forceinline__ unsigned short f2bf(float f)
{
    unsigned u = __builtin_bit_cast(unsigned, f);
    u += 0x7fffu + ((u >> 16) & 1u);
    return (unsigned short)(u >> 16);
}
__device__ __forceinline__ float bf2f(unsigned short s)
{
    return __builtin_bit_cast(float, ((unsigned)s) << 16);
}

// ---------------------------------------------------------------------------
// Reference points: ref[b,s,l,{x,y}]
// ---------------------------------------------------------------------------
__global__ void compute_ref_kernel(const float* __restrict__ vr, float* __restrict__ refpts)
{
    int q = blockIdx.x * blockDim.x + threadIdx.x;
    if (q >= M_N) return;
    int b = q / S_N;
    int s = q - b * S_N;
    const int Hs[4] = {100, 50, 25, 13};
    const int Ws[4] = {152, 76, 38, 19};
    int l0, i, j;
    if (s < 15200)      { l0 = 0; i = s / 152; j = s - i * 152; }
    else if (s < 19000) { int t = s - 15200; l0 = 1; i = t / 76; j = t - i * 76; }
    else if (s < 19950) { int t = s - 19000; l0 = 2; i = t / 38; j = t - i * 38; }
    else                { int t = s - 19950; l0 = 3; i = t / 19; j = t - i * 19; }
    float ry = (i + 0.5f) / (vr[(b * 4 + l0) * 2 + 1] * (float)Hs[l0]);
    float rx = (j + 0.5f) / (vr[(b * 4 + l0) * 2 + 0] * (float)Ws[l0]);
#pragma unroll
    for (int l = 0; l < 4; ++l) {
        refpts[(size_t)q * 8 + l * 2 + 0] = rx * vr[(b * 4 + l) * 2 + 0];
        refpts[(size_t)q * 8 + l * 2 + 1] = ry * vr[(b * 4 + l) * 2 + 1];
    }
}

// ---------------------------------------------------------------------------
// Weight prep: W[K][Nsrc] fp32 -> Wt[rowOff+n][K] bf16 (dst row-stride dstN)
// ---------------------------------------------------------------------------
__global__ __launch_bounds__(256) void transpose_w_kernel(
    const float* __restrict__ W, unsigned short* __restrict__ Wt,
    int K, int Nsrc, int dstN, int rowOff)
{
    __shared__ float t[32][33];
    const float* Wl = W + (size_t)blockIdx.z * K * Nsrc;
    unsigned short* Wtl = Wt + (size_t)blockIdx.z * K * dstN;
    int n0 = blockIdx.x * 32, k0 = blockIdx.y * 32;
    int tx = threadIdx.x & 31, ty = threadIdx.x >> 5;
#pragma unroll
    for (int r = 0; r < 32; r += 8)
        t[ty + r][tx] = Wl[(size_t)(k0 + ty + r) * Nsrc + n0 + tx];
    __syncthreads();
#pragma unroll
    for (int r = 0; r < 32; r += 8)
        Wtl[(size_t)(rowOff + n0 + ty + r) * K + k0 + tx] = f2bf(t[tx][ty + r]);
}

__global__ void boa_kernel(const float* __restrict__ boff, const float* __restrict__ ba,
                           float* __restrict__ boa)
{
    int i = blockIdx.x, j = threadIdx.x;   // 6 x 384
    boa[i * 384 + j] = (j < 256) ? boff[i * 256 + j] : ba[i * 128 + j - 256];
}

// init: out = src; outb = bf16(src); qb = bf16(src + pos)
__global__ __launch_bounds__(256) void init_kernel(
    const float* __restrict__ src, const float* __restrict__ pos,
    float* __restrict__ out, unsigned short* __restrict__ outb,
    unsigned short* __restrict__ qb)
{
    size_t i = (size_t)blockIdx.x * 256 + threadIdx.x;
    float s = src[i];
    out[i]  = s;
    outb[i] = f2bf(s);
    qb[i]   = f2bf(s + pos[i]);
}

// ---------------------------------------------------------------------------
// bf16 MFMA GEMM: C = A @ Wt^T + bias.  128x128 tile, BK=64.
// mode: 1 = bf16 out, 2 = bf16 out + relu
// ---------------------------------------------------------------------------
__global__ __launch_bounds__(256) void gemm_bf16(
    const unsigned short* __restrict__ A, const unsigned short* __restrict__ Wt,
    const float* __restrict__ bias, unsigned short* __restrict__ C,
    int M, int N, int K, int mode)
{
    __shared__ short As[128 * 72];
    __shared__ short Bs[128 * 72];
    const int tid  = threadIdx.x;
    const int m0   = blockIdx.x * 128, n0 = blockIdx.y * 128;
    const int lane = tid & 63, wave = tid >> 6;
    const int wm   = (wave & 1) * 64, wn = (wave >> 1) * 64;
    const int quad = lane >> 4, lm = lane & 15;
    f32x4 acc[4][4] = {};
    const int ar = tid >> 1, ac = (tid & 1) * 32;
    const int gm = m0 + ar;

    for (int k0 = 0; k0 < K; k0 += 64) {
        short8 s[4];
        if (gm < M) {
            const unsigned short* ap = A + (size_t)gm * K + k0 + ac;
#pragma unroll
            for (int i = 0; i < 4; ++i) s[i] = *(const short8*)(ap + 8 * i);
        } else {
#pragma unroll
            for (int i = 0; i < 4; ++i) s[i] = short8{0,0,0,0,0,0,0,0};
        }
        short* da = &As[ar * 72 + ac];
#pragma unroll
        for (int i = 0; i < 4; ++i) *(short8*)(da + i * 8) = s[i];
        const unsigned short* wp = Wt + (size_t)(n0 + ar) * K + k0 + ac;
        short* db = &Bs[ar * 72 + ac];
#pragma unroll
        for (int i = 0; i < 4; ++i) *(short8*)(db + i * 8) = *(const short8*)(wp + i * 8);
        __syncthreads();
#pragma unroll
        for (int ks = 0; ks < 2; ++ks) {
            short8 af[4], bf[4];
#pragma unroll
            for (int mi = 0; mi < 4; ++mi)
                af[mi] = *(short8*)&As[(wm + mi * 16 + lm) * 72 + ks * 32 + quad * 8];
#pragma unroll
            for (int ni = 0; ni < 4; ++ni)
                bf[ni] = *(short8*)&Bs[(wn + ni * 16 + lm) * 72 + ks * 32 + quad * 8];
#pragma unroll
            for (int mi = 0; mi < 4; ++mi)
#pragma unroll
                for (int ni = 0; ni < 4; ++ni)
                    acc[mi][ni] = __builtin_amdgcn_mfma_f32_16x16x32_bf16(
                        af[mi], bf[ni], acc[mi][ni], 0, 0, 0);
        }
        __syncthreads();
    }
    const bool dorelu = (mode == 2);
#pragma unroll
    for (int ni = 0; ni < 4; ++ni) {
        int gc = n0 + wn + ni * 16 + lm;
        float bb = bias[gc];
#pragma unroll
        for (int mi = 0; mi < 4; ++mi)
#pragma unroll
            for (int j = 0; j < 4; ++j) {
                int gr = m0 + wm + mi * 16 + quad * 4 + j;
                if (gr < M) {
                    float v = acc[mi][ni][j] + bb;
                    if (dorelu) v = fmaxf(v, 0.f);
                    C[(size_t)gr * N + gc] = f2bf(v);
                }
            }
    }
}

// ---------------------------------------------------------------------------
// Wide bf16 GEMM: 128x256 tile, BK=64.  Better ds_read:MFMA ratio (24:64/k0).
// mode: 1 = bf16 out, 2 = bf16 out + relu.  N multiple of 256.
// ---------------------------------------------------------------------------
__global__ __launch_bounds__(256, 2) void gemm_bf16_wide(
    const unsigned short* __restrict__ A, const unsigned short* __restrict__ Wt,
    const float* __restrict__ bias, unsigned short* __restrict__ C,
    int M, int N, int K, int mode)
{
    __shared__ short As[128 * 72];
    __shared__ short Bs[256 * 72];
    const int tid  = threadIdx.x;
    const int m0   = blockIdx.x * 128, n0 = blockIdx.y * 256;
    const int lane = tid & 63, wave = tid >> 6;
    const int wm   = (wave & 1) * 64, wn = (wave >> 1) * 128;
    const int quad = lane >> 4, lm = lane & 15;
    f32x4 acc[4][8] = {};
    const int ar = tid >> 1, ac = (tid & 1) * 32;
    const int gm = m0 + ar;

    for (int k0 = 0; k0 < K; k0 += 64) {
        short8 s[4];
        if (gm < M) {
            const unsigned short* ap = A + (size_t)gm * K + k0 + ac;
#pragma unroll
            for (int i = 0; i < 4; ++i) s[i] = *(const short8*)(ap + 8 * i);
        } else {
#pragma unroll
            for (int i = 0; i < 4; ++i) s[i] = short8{0,0,0,0,0,0,0,0};
        }
        short* da = &As[ar * 72 + ac];
#pragma unroll
        for (int i = 0; i < 4; ++i) *(short8*)(da + i * 8) = s[i];
        const unsigned short* wp = Wt + (size_t)(n0 + tid) * K + k0;
        short* db = &Bs[tid * 72];
#pragma unroll
        for (int i = 0; i < 8; ++i) *(short8*)(db + i * 8) = *(const short8*)(wp + i * 8);
        __syncthreads();
#pragma unroll
        for (int ks = 0; ks < 2; ++ks) {
            short8 af[4], bf[8];
#pragma unroll
            for (int mi = 0; mi < 4; ++mi)
                af[mi] = *(short8*)&As[(wm + mi * 16 + lm) * 72 + ks * 32 + quad * 8];
#pragma unroll
            for (int ni = 0; ni < 8; ++ni)
                bf[ni] = *(short8*)&Bs[(wn + ni * 16 + lm) * 72 + ks * 32 + quad * 8];
#pragma unroll
            for (int mi = 0; mi < 4; ++mi)
#pragma unroll
                for (int ni = 0; ni < 8; ++ni)
                    acc[mi][ni] = __builtin_amdgcn_mfma_f32_16x16x32_bf16(
                        af[mi], bf[ni], acc[mi][ni], 0, 0, 0);
        }
        __syncthreads();
    }
    const bool dorelu = (mode == 2);
#pragma unroll
    for (int ni = 0; ni < 8; ++ni) {
        int gc = n0 + wn + ni * 16 + lm;
        float bb = bias[gc];
#pragma unroll
        for (int mi = 0; mi < 4; ++mi)
#pragma unroll
            for (int j = 0; j < 4; ++j) {
                int gr = m0 + wm + mi * 16 + quad * 4 + j;
                if (gr < M) {
                    float v = acc[mi][ni][j] + bb;
                    if (dorelu) v = fmaxf(v, 0.f);
                    C[(size_t)gr * N + gc] = f2bf(v);
                }
            }
    }
}

// ---------------------------------------------------------------------------
// Fused GEMM (N=256 full row) + residual + LayerNorm.
// ---------------------------------------------------------------------------
__global__ __launch_bounds__(256, 2) void gemm_bf16_ln(
    const unsigned short* __restrict__ A, const unsigned short* __restrict__ Wt,
    const float* __restrict__ bias, float* __restrict__ out,
    unsigned short* __restrict__ outb, const float* __restrict__ g,
    const float* __restrict__ beta, const float* __restrict__ pos,
    unsigned short* __restrict__ qb, int M, int K)
{
    __shared__ short As[128 * 72];
    __shared__ short Bs[256 * 72];
    __shared__ float red[128][4];
    __shared__ float mstat[128][2];
    const int tid  = threadIdx.x;
    const int m0   = blockIdx.x * 128;
    const int lane = tid & 63, wave = tid >> 6;
    const int wm   = (wave & 1) * 64, wn = (wave >> 1) * 128;
    const int quad = lane >> 4, lm = lane & 15;
    f32x4 acc[4][8] = {};
    const int ar = tid >> 1, ac = (tid & 1) * 32;
    const int gm = m0 + ar;

    for (int k0 = 0; k0 < K; k0 += 64) {
        short8 s[4];
        if (gm < M) {
            const unsigned short* ap = A + (size_t)gm * K + k0 + ac;
#pragma unroll
            for (int i = 0; i < 4; ++i) s[i] = *(const short8*)(ap + 8 * i);
        } else {
#pragma unroll
            for (int i = 0; i < 4; ++i) s[i] = short8{0,0,0,0,0,0,0,0};
        }
        short* da = &As[ar * 72 + ac];
#pragma unroll
        for (int i = 0; i < 4; ++i) *(short8*)(da + i * 8) = s[i];
        const unsigned short* wp = Wt + (size_t)tid * K + k0;
        short* db = &Bs[tid * 72];
#pragma unroll
        for (int i = 0; i < 8; ++i) *(short8*)(db + i * 8) = *(const short8*)(wp + i * 8);
        __syncthreads();
#pragma unroll
        for (int ks = 0; ks < 2; ++ks) {
            short8 af[4], bf[8];
#pragma unroll
            for (int mi = 0; mi < 4; ++mi)
                af[mi] = *(short8*)&As[(wm + mi * 16 + lm) * 72 + ks * 32 + quad * 8];
#pragma unroll
            for (int ni = 0; ni < 8; ++ni)
                bf[ni] = *(short8*)&Bs[(wn + ni * 16 + lm) * 72 + ks * 32 + quad * 8];
#pragma unroll
            for (int mi = 0; mi < 4; ++mi)
#pragma unroll
                for (int ni = 0; ni < 8; ++ni)
                    acc[mi][ni] = __builtin_amdgcn_mfma_f32_16x16x32_bf16(
                        af[mi], bf[ni], acc[mi][ni], 0, 0, 0);
        }
        __syncthreads();
    }
    float g8[8], b8[8], bi8[8];
#pragma unroll
    for (int ni = 0; ni < 8; ++ni) {
        int gc = wn + ni * 16 + lm;
        g8[ni] = g[gc]; b8[ni] = beta[gc]; bi8[ni] = bias[gc];
    }
#pragma unroll
    for (int mi = 0; mi < 4; ++mi)
#pragma unroll
        for (int j = 0; j < 4; ++j) {
            int r  = wm + mi * 16 + quad * 4 + j;
            int gr = m0 + r;
            float s = 0.f, sq = 0.f;
            if (gr < M) {
#pragma unroll
                for (int ni = 0; ni < 8; ++ni) {
                    float v = acc[mi][ni][j] + bi8[ni] + out[(size_t)gr * 256 + wn + ni * 16 + lm];
                    acc[mi][ni][j] = v;
                    s += v; sq += v * v;
                }
            }
#pragma unroll
            for (int o = 1; o < 16; o <<= 1) {
                s  += __shfl_xor(s, o, 64);
                sq += __shfl_xor(sq, o, 64);
            }
            if (lm == 0) { red[r][(wn >> 7) * 2 + 0] = s; red[r][(wn >> 7) * 2 + 1] = sq; }
        }
    __syncthreads();
    if (tid < 128) {
        float S = red[tid][0] + red[tid][2];
        float Q = red[tid][1] + red[tid][3];
        float mean = S * (1.f / 256.f);
        float var  = Q * (1.f / 256.f) - mean * mean;
        mstat[tid][0] = mean;
        mstat[tid][1] = rsqrtf(var + 1e-5f);
    }
    __syncthreads();
#pragma unroll
    for (int mi = 0; mi < 4; ++mi)
#pragma unroll
        for (int j = 0; j < 4; ++j) {
            int r  = wm + mi * 16 + quad * 4 + j;
            int gr = m0 + r;
            if (gr >= M) continue;
            float mean = mstat[r][0], rs = mstat[r][1];
#pragma unroll
            for (int ni = 0; ni < 8; ++ni) {
                size_t idx = (size_t)gr * 256 + wn + ni * 16 + lm;
                float v = (acc[mi][ni][j] - mean) * rs * g8[ni] + b8[ni];
                out[idx]  = v;
                outb[idx] = f2bf(v);
                if (qb) qb[idx] = f2bf(v + pos[idx]);
            }
        }
}

// ---------------------------------------------------------------------------
// MSDA sampler v4: 2 queries/block, XCD-aware swizzle for L2 locality.
// Each XCD (blockIdx % 8 under round-robin dispatch) covers a contiguous
// band of queries -> its gather footprint (~2.7 MB) fits the 4 MB per-XCD L2.
// ---------------------------------------------------------------------------
#define NBLK ((M_N + 1) / 2)          // 20197 logical blocks
#define CHUNK_B ((NBLK + 7) / 8)      // 2525 per XCD
__global__ __launch_bounds__(256) void msda_sample_kernel(
    const unsigned short* __restrict__ value,  // bf16 (B,S,8,32)
    const unsigned short* __restrict__ oa,     // bf16 (B,S,384): 256 off | 128 logits
    const float* __restrict__ refpts,          // fp32 (B,S,4,2)
    unsigned short* __restrict__ accb)         // bf16 (B,S,256)
{
    __shared__ int pts[272 * 10];
    const int bb = (blockIdx.x & 7) * CHUNK_B + (blockIdx.x >> 3);
    if (bb >= NBLK) return;
    const int tid = threadIdx.x;
    const int q0  = bb * 2;
    {
        const int qq = tid >> 7;
        const int q  = q0 + qq;
        const int jj = tid & 127;
        const int h  = jj >> 4, l = (jj >> 2) & 3, t = jj & 15;
        const int b  = q / S_N;
        const int Wi = 152 >> l;
        const int Hi = (100 >> l) + (l == 3);
        const float Wf = (float)Wi, Hf = (float)Hi;
        const int start = (l < 1) ? 0 : (l < 2) ? 15200 : (l < 3) ? 19000 : 19950;
        const unsigned short* oq = oa + (size_t)q * 384;
        unsigned op = *(const unsigned*)(oq + jj * 2);
        float ox = __builtin_bit_cast(float, op << 16);
        float oy = __builtin_bit_cast(float, op & 0xffff0000u);
        float2 rp = *(const float2*)(refpts + (size_t)q * 8 + l * 2);
        float logit = bf2f(oq[256 + jj]);
        float mx = logit;
#pragma unroll
        for (int o = 1; o < 16; o <<= 1) mx = fmaxf(mx, __shfl_xor(mx, o, 64));
        float e = expf(logit - mx);
        float sum = e;
#pragma unroll
        for (int o = 1; o < 16; o <<= 1) sum += __shfl_xor(sum, o, 64);
        float w = e / sum;
        float px = (rp.x + ox / Wf) * Wf - 0.5f;
        float py = (rp.y + oy / Hf) * Hf - 0.5f;
        float x0f = floorf(px), y0f = floorf(py);
        float fx = px - x0f, fy = py - y0f;
        int x0 = (int)x0f, y0 = (int)y0f;
        int base = b * S_N + start;
        int P = qq * 136 + h * 17 + t;
#pragma unroll
        for (int c = 0; c < 4; ++c) {
            int dx = c & 1, dy = c >> 1;
            int xi = x0 + dx, yi = y0 + dy;
            bool valid = (xi >= 0) & (xi < Wi) & (yi >= 0) & (yi < Hi);
            int xc = min(max(xi, 0), Wi - 1);
            int yc = min(max(yi, 0), Hi - 1);
            float cw = (dx ? fx : 1.f - fx) * (dy ? fy : 1.f - fy);
            int offby = ((base + yc * Wi + xc) * 256 + h * 32) * 2;
            pts[P * 10 + c * 2 + 0] = offby;
            pts[P * 10 + c * 2 + 1] = __builtin_bit_cast(int, valid ? w * cw : 0.f);
        }
    }
    __syncthreads();
    const int qq = tid >> 7;
    const int gl = tid & 127;
    const int hh = gl >> 4, lg = gl & 15;
    const int cn = lg & 3;
    const int c8 = (lg >> 2) * 8;
    const char* vb = (const char*)value + c8 * 2;
    float a[8] = {};
    const int Pb = qq * 136 + hh * 17;
#pragma unroll
    for (int t = 0; t < 16; ++t) {
        int2 ow = *(const int2*)&pts[(Pb + t) * 10 + cn * 2];
        float w = __builtin_bit_cast(float, ow.y);
        short8 v8 = *(const short8*)(vb + ow.x);
#pragma unroll
        for (int i = 0; i < 8; ++i)
            a[i] = fmaf(w, bf2f((unsigned short)v8[i]), a[i]);
    }
#pragma unroll
    for (int o = 1; o < 4; o <<= 1)
#pragma unroll
        for (int i = 0; i < 8; ++i) a[i] += __shfl_xor(a[i], o, 64);
    if (cn == 0) {
        int4 pk;
        pk.x = (int)((unsigned)f2bf(a[0]) | ((unsigned)f2bf(a[1]) << 16));
        pk.y = (int)((unsigned)f2bf(a[2]) | ((unsigned)f2bf(a[3]) << 16));
        pk.z = (int)((unsigned)f2bf(a[4]) | ((unsigned)f2bf(a[5]) << 16));
        pk.w = (int)((unsigned)f2bf(a[6]) | ((unsigned)f2bf(a[7]) << 16));
        *(int4*)((char*)accb + ((size_t)(q0 + qq) * 256 + hh * 32 + c8) * 2) = pk;
    }
}

// ---------------------------------------------------------------------------
extern "C" void kernel_launch(void* const* d_in, const int* in_sizes, int n_in,
                              void* d_out, int out_size, void* d_ws, size_t ws_size,
                              hipStream_t stream)
{
    const float* src  = (const float*)d_in[0];
    const float* pos  = (const float*)d_in[1];
    const float* vr   = (const float*)d_in[2];
    const float* Wv   = (const float*)d_in[3];
    const float* bv   = (const float*)d_in[4];
    const float* Woff = (const float*)d_in[5];
    const float* boff = (const float*)d_in[6];
    const float* Wa   = (const float*)d_in[7];
    const float* ba   = (const float*)d_in[8];
    const float* Wo   = (const float*)d_in[9];
    const float* bo   = (const float*)d_in[10];
    const float* g1   = (const float*)d_in[11];
    const float* be1  = (const float*)d_in[12];
    const float* W1   = (const float*)d_in[13];
    const float* b1   = (const float*)d_in[14];
    const float* W2   = (const float*)d_in[15];
    const float* b2   = (const float*)d_in[16];
    const float* g2   = (const float*)d_in[17];
    const float* be2  = (const float*)d_in[18];

    float* out = (float*)d_out;
    float* ws  = (float*)d_ws;
    float* refpts = ws;
    float* valreg = refpts + 323200;
    float* oareg  = valreg + 5170432;
    float* slack  = oareg  + 7755648;
    float* accreg = slack  + 7755648;
    float* qreg   = accreg + 5170432;
    float* obreg  = qreg   + 5170432;
    unsigned short* value_bf = (unsigned short*)valreg;
    unsigned short* oa       = (unsigned short*)oareg;
    unsigned short* hidden   = (unsigned short*)valreg;
    unsigned short* accb     = (unsigned short*)accreg;
    unsigned short* qb       = (unsigned short*)qreg;
    unsigned short* outb     = (unsigned short*)obreg;
    unsigned short* wtv  = (unsigned short*)(obreg + 5170432);
    unsigned short* wtoa = wtv  + 6 * 65536;
    unsigned short* wto  = wtoa + 6 * 98304;
    unsigned short* wt1  = wto  + 6 * 65536;
    unsigned short* wt2  = wt1  + 6 * 262144;
    float* boa = (float*)(wt2 + 6 * 262144);

    dim3 blk(256);
    compute_ref_kernel<<<(M_N + 255) / 256, 256, 0, stream>>>(vr, refpts);
    init_kernel<<<M_N, blk, 0, stream>>>(src, pos, out, outb, qb);
    transpose_w_kernel<<<dim3(8, 8, 6),  blk, 0, stream>>>(Wv,   wtv,  256, 256,  256, 0);
    transpose_w_kernel<<<dim3(8, 8, 6),  blk, 0, stream>>>(Woff, wtoa, 256, 256,  384, 0);
    transpose_w_kernel<<<dim3(4, 8, 6),  blk, 0, stream>>>(Wa,   wtoa, 256, 128,  384, 256);
    transpose_w_kernel<<<dim3(8, 8, 6),  blk, 0, stream>>>(Wo,   wto,  256, 256,  256, 0);
    transpose_w_kernel<<<dim3(32, 8, 6), blk, 0, stream>>>(W1,   wt1,  256, 1024, 1024, 0);
    transpose_w_kernel<<<dim3(8, 32, 6), blk, 0, stream>>>(W2,   wt2,  1024, 256, 256, 0);
    boa_kernel<<<6, 384, 0, stream>>>(boff, ba, boa);

    const int mt = (M_N + 127) / 128;   // 316
    for (int i = 0; i < 6; ++i) {
        gemm_bf16<<<dim3(mt, 3), blk, 0, stream>>>(qb, wtoa + (size_t)i * 98304,
                                                   boa + i * 384, oa, M_N, 384, 256, 1);
        gemm_bf16<<<dim3(mt, 2), blk, 0, stream>>>(outb, wtv + (size_t)i * 65536,
                                                   bv + i * 256, value_bf, M_N, 256, 256, 1);
        msda_sample_kernel<<<8 * CHUNK_B, blk, 0, stream>>>(value_bf, oa, refpts, accb);
        gemm_bf16_ln<<<mt, blk, 0, stream>>>(accb, wto + (size_t)i * 65536, bo + i * 256,
                                             out, outb, g1 + i * 256, be1 + i * 256,
                                             nullptr, nullptr, M_N, 256);
        gemm_bf16_wide<<<dim3(mt, 4), blk, 0, stream>>>(outb, wt1 + (size_t)i * 262144,
                                                        b1 + i * 1024, hidden, M_N, 1024, 256, 2);
        gemm_bf16_ln<<<mt, blk, 0, stream>>>(hidden, wt2 + (size_t)i * 262144, b2 + i * 256,
                                             out, outb, g2 + i * 256, be2 + i * 256,
                                             pos, qb, M_N, 1024);
    }
}

// Round 7
// 2614.513 us; speedup vs baseline: 1.0393x; 1.0393x over previous
//
#include <hip/hip_runtime.h>
#include <math.h>

#define B_N   2
#define S_N   20197
#define M_N   (B_N * S_N)   // 40394 rows
#define D_N   256
#define NH_N  8
#define HD_N  32
#define DFF_N 1024

typedef __attribute__((ext_vector_type(8))) short short8;
typedef __attribute__((ext_vector_type(4))) float f32x4;
typedef __attribute__((ext_vector_type(2))) float f32x2;

__device__ __forceinline__ unsigned short f2bf(float f)
{
    unsigned u = __builtin_bit_cast(unsigned, f);
    u += 0x7fffu + ((u >> 16) & 1u);
    return (unsigned short)(u >> 16);
}
__device__ __forceinline__ float bf2f(unsigned short s)
{
    return __builtin_bit_cast(float, ((unsigned)s) << 16);
}

// ---------------------------------------------------------------------------
// Reference points: ref[b,s,l,{x,y}]
// ---------------------------------------------------------------------------
__global__ void compute_ref_kernel(const float* __restrict__ vr, float* __restrict__ refpts)
{
    int q = blockIdx.x * blockDim.x + threadIdx.x;
    if (q >= M_N) return;
    int b = q / S_N;
    int s = q - b * S_N;
    const int Hs[4] = {100, 50, 25, 13};
    const int Ws[4] = {152, 76, 38, 19};
    int l0, i, j;
    if (s < 15200)      { l0 = 0; i = s / 152; j = s - i * 152; }
    else if (s < 19000) { int t = s - 15200; l0 = 1; i = t / 76; j = t - i * 76; }
    else if (s < 19950) { int t = s - 19000; l0 = 2; i = t / 38; j = t - i * 38; }
    else                { int t = s - 19950; l0 = 3; i = t / 19; j = t - i * 19; }
    float ry = (i + 0.5f) / (vr[(b * 4 + l0) * 2 + 1] * (float)Hs[l0]);
    float rx = (j + 0.5f) / (vr[(b * 4 + l0) * 2 + 0] * (float)Ws[l0]);
#pragma unroll
    for (int l = 0; l < 4; ++l) {
        refpts[(size_t)q * 8 + l * 2 + 0] = rx * vr[(b * 4 + l) * 2 + 0];
        refpts[(size_t)q * 8 + l * 2 + 1] = ry * vr[(b * 4 + l) * 2 + 1];
    }
}

// ---------------------------------------------------------------------------
// Weight prep: W[K][Nsrc] fp32 -> Wt[rowOff+n][K] bf16 (dst row-stride dstN)
// ---------------------------------------------------------------------------
__global__ __launch_bounds__(256) void transpose_w_kernel(
    const float* __restrict__ W, unsigned short* __restrict__ Wt,
    int K, int Nsrc, int dstN, int rowOff)
{
    __shared__ float t[32][33];
    const float* Wl = W + (size_t)blockIdx.z * K * Nsrc;
    unsigned short* Wtl = Wt + (size_t)blockIdx.z * K * dstN;
    int n0 = blockIdx.x * 32, k0 = blockIdx.y * 32;
    int tx = threadIdx.x & 31, ty = threadIdx.x >> 5;
#pragma unroll
    for (int r = 0; r < 32; r += 8)
        t[ty + r][tx] = Wl[(size_t)(k0 + ty + r) * Nsrc + n0 + tx];
    __syncthreads();
#pragma unroll
    for (int r = 0; r < 32; r += 8)
        Wtl[(size_t)(rowOff + n0 + ty + r) * K + k0 + tx] = f2bf(t[tx][ty + r]);
}

__global__ void boa_kernel(const float* __restrict__ boff, const float* __restrict__ ba,
                           float* __restrict__ boa)
{
    int i = blockIdx.x, j = threadIdx.x;   // 6 x 384
    boa[i * 384 + j] = (j < 256) ? boff[i * 256 + j] : ba[i * 128 + j - 256];
}

// init: out = src; outb = bf16(src); qb = bf16(src + pos)
__global__ __launch_bounds__(256) void init_kernel(
    const float* __restrict__ src, const float* __restrict__ pos,
    float* __restrict__ out, unsigned short* __restrict__ outb,
    unsigned short* __restrict__ qb)
{
    size_t i = (size_t)blockIdx.x * 256 + threadIdx.x;
    float s = src[i];
    out[i]  = s;
    outb[i] = f2bf(s);
    qb[i]   = f2bf(s + pos[i]);
}

// ---------------------------------------------------------------------------
// bf16 MFMA GEMM: C = A @ Wt^T + bias.  128x128 tile, BK=64.
// mode: 1 = bf16 out, 2 = bf16 out + relu
// ---------------------------------------------------------------------------
__global__ __launch_bounds__(256) void gemm_bf16(
    const unsigned short* __restrict__ A, const unsigned short* __restrict__ Wt,
    const float* __restrict__ bias, unsigned short* __restrict__ C,
    int M, int N, int K, int mode)
{
    __shared__ short As[128 * 72];
    __shared__ short Bs[128 * 72];
    const int tid  = threadIdx.x;
    const int m0   = blockIdx.x * 128, n0 = blockIdx.y * 128;
    const int lane = tid & 63, wave = tid >> 6;
    const int wm   = (wave & 1) * 64, wn = (wave >> 1) * 64;
    const int quad = lane >> 4, lm = lane & 15;
    f32x4 acc[4][4] = {};
    const int ar = tid >> 1, ac = (tid & 1) * 32;
    const int gm = m0 + ar;

    for (int k0 = 0; k0 < K; k0 += 64) {
        short8 s[4];
        if (gm < M) {
            const unsigned short* ap = A + (size_t)gm * K + k0 + ac;
#pragma unroll
            for (int i = 0; i < 4; ++i) s[i] = *(const short8*)(ap + 8 * i);
        } else {
#pragma unroll
            for (int i = 0; i < 4; ++i) s[i] = short8{0,0,0,0,0,0,0,0};
        }
        short* da = &As[ar * 72 + ac];
#pragma unroll
        for (int i = 0; i < 4; ++i) *(short8*)(da + i * 8) = s[i];
        const unsigned short* wp = Wt + (size_t)(n0 + ar) * K + k0 + ac;
        short* db = &Bs[ar * 72 + ac];
#pragma unroll
        for (int i = 0; i < 4; ++i) *(short8*)(db + i * 8) = *(const short8*)(wp + i * 8);
        __syncthreads();
#pragma unroll
        for (int ks = 0; ks < 2; ++ks) {
            short8 af[4], bf[4];
#pragma unroll
            for (int mi = 0; mi < 4; ++mi)
                af[mi] = *(short8*)&As[(wm + mi * 16 + lm) * 72 + ks * 32 + quad * 8];
#pragma unroll
            for (int ni = 0; ni < 4; ++ni)
                bf[ni] = *(short8*)&Bs[(wn + ni * 16 + lm) * 72 + ks * 32 + quad * 8];
#pragma unroll
            for (int mi = 0; mi < 4; ++mi)
#pragma unroll
                for (int ni = 0; ni < 4; ++ni)
                    acc[mi][ni] = __builtin_amdgcn_mfma_f32_16x16x32_bf16(
                        af[mi], bf[ni], acc[mi][ni], 0, 0, 0);
        }
        __syncthreads();
    }
    const bool dorelu = (mode == 2);
#pragma unroll
    for (int ni = 0; ni < 4; ++ni) {
        int gc = n0 + wn + ni * 16 + lm;
        float bb = bias[gc];
#pragma unroll
        for (int mi = 0; mi < 4; ++mi)
#pragma unroll
            for (int j = 0; j < 4; ++j) {
                int gr = m0 + wm + mi * 16 + quad * 4 + j;
                if (gr < M) {
                    float v = acc[mi][ni][j] + bb;
                    if (dorelu) v = fmaxf(v, 0.f);
                    C[(size_t)gr * N + gc] = f2bf(v);
                }
            }
    }
}

// ---------------------------------------------------------------------------
// Fused GEMM (N=256 full row) + residual + LayerNorm.
// ---------------------------------------------------------------------------
__global__ __launch_bounds__(256, 2) void gemm_bf16_ln(
    const unsigned short* __restrict__ A, const unsigned short* __restrict__ Wt,
    const float* __restrict__ bias, float* __restrict__ out,
    unsigned short* __restrict__ outb, const float* __restrict__ g,
    const float* __restrict__ beta, const float* __restrict__ pos,
    unsigned short* __restrict__ qb, int M, int K)
{
    __shared__ short As[128 * 72];
    __shared__ short Bs[256 * 72];
    __shared__ float red[128][4];
    __shared__ float mstat[128][2];
    const int tid  = threadIdx.x;
    const int m0   = blockIdx.x * 128;
    const int lane = tid & 63, wave = tid >> 6;
    const int wm   = (wave & 1) * 64, wn = (wave >> 1) * 128;
    const int quad = lane >> 4, lm = lane & 15;
    f32x4 acc[4][8] = {};
    const int ar = tid >> 1, ac = (tid & 1) * 32;
    const int gm = m0 + ar;

    for (int k0 = 0; k0 < K; k0 += 64) {
        short8 s[4];
        if (gm < M) {
            const unsigned short* ap = A + (size_t)gm * K + k0 + ac;
#pragma unroll
            for (int i = 0; i < 4; ++i) s[i] = *(const short8*)(ap + 8 * i);
        } else {
#pragma unroll
            for (int i = 0; i < 4; ++i) s[i] = short8{0,0,0,0,0,0,0,0};
        }
        short* da = &As[ar * 72 + ac];
#pragma unroll
        for (int i = 0; i < 4; ++i) *(short8*)(da + i * 8) = s[i];
        const unsigned short* wp = Wt + (size_t)tid * K + k0;
        short* db = &Bs[tid * 72];
#pragma unroll
        for (int i = 0; i < 8; ++i) *(short8*)(db + i * 8) = *(const short8*)(wp + i * 8);
        __syncthreads();
#pragma unroll
        for (int ks = 0; ks < 2; ++ks) {
            short8 af[4], bf[8];
#pragma unroll
            for (int mi = 0; mi < 4; ++mi)
                af[mi] = *(short8*)&As[(wm + mi * 16 + lm) * 72 + ks * 32 + quad * 8];
#pragma unroll
            for (int ni = 0; ni < 8; ++ni)
                bf[ni] = *(short8*)&Bs[(wn + ni * 16 + lm) * 72 + ks * 32 + quad * 8];
#pragma unroll
            for (int mi = 0; mi < 4; ++mi)
#pragma unroll
                for (int ni = 0; ni < 8; ++ni)
                    acc[mi][ni] = __builtin_amdgcn_mfma_f32_16x16x32_bf16(
                        af[mi], bf[ni], acc[mi][ni], 0, 0, 0);
        }
        __syncthreads();
    }
    float g8[8], b8[8], bi8[8];
#pragma unroll
    for (int ni = 0; ni < 8; ++ni) {
        int gc = wn + ni * 16 + lm;
        g8[ni] = g[gc]; b8[ni] = beta[gc]; bi8[ni] = bias[gc];
    }
#pragma unroll
    for (int mi = 0; mi < 4; ++mi)
#pragma unroll
        for (int j = 0; j < 4; ++j) {
            int r  = wm + mi * 16 + quad * 4 + j;
            int gr = m0 + r;
            float s = 0.f, sq = 0.f;
            if (gr < M) {
#pragma unroll
                for (int ni = 0; ni < 8; ++ni) {
                    float v = acc[mi][ni][j] + bi8[ni] + out[(size_t)gr * 256 + wn + ni * 16 + lm];
                    acc[mi][ni][j] = v;
                    s += v; sq += v * v;
                }
            }
#pragma unroll
            for (int o = 1; o < 16; o <<= 1) {
                s  += __shfl_xor(s, o, 64);
                sq += __shfl_xor(sq, o, 64);
            }
            if (lm == 0) { red[r][(wn >> 7) * 2 + 0] = s; red[r][(wn >> 7) * 2 + 1] = sq; }
        }
    __syncthreads();
    if (tid < 128) {
        float S = red[tid][0] + red[tid][2];
        float Q = red[tid][1] + red[tid][3];
        float mean = S * (1.f / 256.f);
        float var  = Q * (1.f / 256.f) - mean * mean;
        mstat[tid][0] = mean;
        mstat[tid][1] = rsqrtf(var + 1e-5f);
    }
    __syncthreads();
#pragma unroll
    for (int mi = 0; mi < 4; ++mi)
#pragma unroll
        for (int j = 0; j < 4; ++j) {
            int r  = wm + mi * 16 + quad * 4 + j;
            int gr = m0 + r;
            if (gr >= M) continue;
            float mean = mstat[r][0], rs = mstat[r][1];
#pragma unroll
            for (int ni = 0; ni < 8; ++ni) {
                size_t idx = (size_t)gr * 256 + wn + ni * 16 + lm;
                float v = (acc[mi][ni][j] - mean) * rs * g8[ni] + b8[ni];
                out[idx]  = v;
                outb[idx] = f2bf(v);
                if (qb) qb[idx] = f2bf(v + pos[idx]);
            }
        }
}

// ---------------------------------------------------------------------------
// MSDA sampler v5: 1 query / 128-thread block, XCD swizzle, batched gathers.
// Phase 1 (128 thr = 128 pts): softmax + corner offsets/weights -> LDS.
// Phase 2: lanes = 8 heads x 4 corners x 4 octets; 8 gathers in flight.
// ---------------------------------------------------------------------------
#define CHUNK_B ((M_N + 7) / 8)      // 5050 queries per XCD band
__global__ __launch_bounds__(128) void msda_sample_kernel(
    const unsigned short* __restrict__ value,  // bf16 (B,S,8,32)
    const unsigned short* __restrict__ oa,     // bf16 (B,S,384): 256 off | 128 logits
    const float* __restrict__ refpts,          // fp32 (B,S,4,2)
    unsigned short* __restrict__ accb)         // bf16 (B,S,256)
{
    __shared__ int pts[136 * 10];   // 8 heads x 17-point stride x 10 ints
    const int q = (blockIdx.x & 7) * CHUNK_B + (blockIdx.x >> 3);
    if (q >= M_N) return;
    const int tid = threadIdx.x;
    {
        const int jj = tid;                    // 0..127 = (h,l,p)
        const int h  = jj >> 4, l = (jj >> 2) & 3, t = jj & 15;
        const int b  = q / S_N;
        const int Wi = 152 >> l;
        const int Hi = (100 >> l) + (l == 3);
        const float Wf = (float)Wi, Hf = (float)Hi;
        const int start = (l < 1) ? 0 : (l < 2) ? 15200 : (l < 3) ? 19000 : 19950;
        const unsigned short* oq = oa + (size_t)q * 384;
        unsigned op = *(const unsigned*)(oq + jj * 2);
        float ox = __builtin_bit_cast(float, op << 16);
        float oy = __builtin_bit_cast(float, op & 0xffff0000u);
        float2 rp = *(const float2*)(refpts + (size_t)q * 8 + l * 2);
        float logit = bf2f(oq[256 + jj]);
        float mx = logit;
#pragma unroll
        for (int o = 1; o < 16; o <<= 1) mx = fmaxf(mx, __shfl_xor(mx, o, 64));
        float e = expf(logit - mx);
        float sum = e;
#pragma unroll
        for (int o = 1; o < 16; o <<= 1) sum += __shfl_xor(sum, o, 64);
        float w = e / sum;
        float px = (rp.x + ox / Wf) * Wf - 0.5f;
        float py = (rp.y + oy / Hf) * Hf - 0.5f;
        float x0f = floorf(px), y0f = floorf(py);
        float fx = px - x0f, fy = py - y0f;
        int x0 = (int)x0f, y0 = (int)y0f;
        int base = b * S_N + start;
        int P = h * 17 + t;
#pragma unroll
        for (int c = 0; c < 4; ++c) {
            int dx = c & 1, dy = c >> 1;
            int xi = x0 + dx, yi = y0 + dy;
            bool valid = (xi >= 0) & (xi < Wi) & (yi >= 0) & (yi < Hi);
            int xc = min(max(xi, 0), Wi - 1);
            int yc = min(max(yi, 0), Hi - 1);
            float cw = (dx ? fx : 1.f - fx) * (dy ? fy : 1.f - fy);
            int offby = ((base + yc * Wi + xc) * 256 + h * 32) * 2;
            pts[P * 10 + c * 2 + 0] = offby;
            pts[P * 10 + c * 2 + 1] = __builtin_bit_cast(int, valid ? w * cw : 0.f);
        }
    }
    __syncthreads();
    const int hh = tid >> 4, lg = tid & 15;
    const int cn = lg & 3;                 // corner
    const int c8 = (lg >> 2) * 8;          // channel octet
    const char* vb = (const char*)value + c8 * 2;
    f32x2 a[4] = {};                       // 8 channels as 4 float2 (pk_fma)
    const int Pb = hh * 17;
#pragma unroll
    for (int t0 = 0; t0 < 16; t0 += 8) {
        int2 ow[8];
#pragma unroll
        for (int i = 0; i < 8; ++i)
            ow[i] = *(const int2*)&pts[(Pb + t0 + i) * 10 + cn * 2];
        int4 v[8];
#pragma unroll
        for (int i = 0; i < 8; ++i)
            v[i] = *(const int4*)(vb + ow[i].x);
#pragma unroll
        for (int i = 0; i < 8; ++i) {
            float w = __builtin_bit_cast(float, ow[i].y);
            f32x2 wv = {w, w};
            unsigned d;
            d = (unsigned)v[i].x;
            a[0] += wv * f32x2{__builtin_bit_cast(float, d << 16),
                               __builtin_bit_cast(float, d & 0xffff0000u)};
            d = (unsigned)v[i].y;
            a[1] += wv * f32x2{__builtin_bit_cast(float, d << 16),
                               __builtin_bit_cast(float, d & 0xffff0000u)};
            d = (unsigned)v[i].z;
            a[2] += wv * f32x2{__builtin_bit_cast(float, d << 16),
                               __builtin_bit_cast(float, d & 0xffff0000u)};
            d = (unsigned)v[i].w;
            a[3] += wv * f32x2{__builtin_bit_cast(float, d << 16),
                               __builtin_bit_cast(float, d & 0xffff0000u)};
        }
    }
#pragma unroll
    for (int o = 1; o < 4; o <<= 1)
#pragma unroll
        for (int i = 0; i < 4; ++i) {
            a[i].x += __shfl_xor(a[i].x, o, 64);
            a[i].y += __shfl_xor(a[i].y, o, 64);
        }
    if (cn == 0) {
        int4 pk;
        pk.x = (int)((unsigned)f2bf(a[0].x) | ((unsigned)f2bf(a[0].y) << 16));
        pk.y = (int)((unsigned)f2bf(a[1].x) | ((unsigned)f2bf(a[1].y) << 16));
        pk.z = (int)((unsigned)f2bf(a[2].x) | ((unsigned)f2bf(a[2].y) << 16));
        pk.w = (int)((unsigned)f2bf(a[3].x) | ((unsigned)f2bf(a[3].y) << 16));
        *(int4*)((char*)accb + ((size_t)q * 256 + hh * 32 + c8) * 2) = pk;
    }
}

// ---------------------------------------------------------------------------
extern "C" void kernel_launch(void* const* d_in, const int* in_sizes, int n_in,
                              void* d_out, int out_size, void* d_ws, size_t ws_size,
                              hipStream_t stream)
{
    const float* src  = (const float*)d_in[0];
    const float* pos  = (const float*)d_in[1];
    const float* vr   = (const float*)d_in[2];
    const float* Wv   = (const float*)d_in[3];
    const float* bv   = (const float*)d_in[4];
    const float* Woff = (const float*)d_in[5];
    const float* boff = (const float*)d_in[6];
    const float* Wa   = (const float*)d_in[7];
    const float* ba   = (const float*)d_in[8];
    const float* Wo   = (const float*)d_in[9];
    const float* bo   = (const float*)d_in[10];
    const float* g1   = (const float*)d_in[11];
    const float* be1  = (const float*)d_in[12];
    const float* W1   = (const float*)d_in[13];
    const float* b1   = (const float*)d_in[14];
    const float* W2   = (const float*)d_in[15];
    const float* b2   = (const float*)d_in[16];
    const float* g2   = (const float*)d_in[17];
    const float* be2  = (const float*)d_in[18];

    float* out = (float*)d_out;
    float* ws  = (float*)d_ws;
    float* refpts = ws;
    float* valreg = refpts + 323200;
    float* oareg  = valreg + 5170432;
    float* slack  = oareg  + 7755648;
    float* accreg = slack  + 7755648;
    float* qreg   = accreg + 5170432;
    float* obreg  = qreg   + 5170432;
    unsigned short* value_bf = (unsigned short*)valreg;
    unsigned short* oa       = (unsigned short*)oareg;
    unsigned short* hidden   = (unsigned short*)valreg;
    unsigned short* accb     = (unsigned short*)accreg;
    unsigned short* qb       = (unsigned short*)qreg;
    unsigned short* outb     = (unsigned short*)obreg;
    unsigned short* wtv  = (unsigned short*)(obreg + 5170432);
    unsigned short* wtoa = wtv  + 6 * 65536;
    unsigned short* wto  = wtoa + 6 * 98304;
    unsigned short* wt1  = wto  + 6 * 65536;
    unsigned short* wt2  = wt1  + 6 * 262144;
    float* boa = (float*)(wt2 + 6 * 262144);

    dim3 blk(256);
    compute_ref_kernel<<<(M_N + 255) / 256, 256, 0, stream>>>(vr, refpts);
    init_kernel<<<M_N, blk, 0, stream>>>(src, pos, out, outb, qb);
    transpose_w_kernel<<<dim3(8, 8, 6),  blk, 0, stream>>>(Wv,   wtv,  256, 256,  256, 0);
    transpose_w_kernel<<<dim3(8, 8, 6),  blk, 0, stream>>>(Woff, wtoa, 256, 256,  384, 0);
    transpose_w_kernel<<<dim3(4, 8, 6),  blk, 0, stream>>>(Wa,   wtoa, 256, 128,  384, 256);
    transpose_w_kernel<<<dim3(8, 8, 6),  blk, 0, stream>>>(Wo,   wto,  256, 256,  256, 0);
    transpose_w_kernel<<<dim3(32, 8, 6), blk, 0, stream>>>(W1,   wt1,  256, 1024, 1024, 0);
    transpose_w_kernel<<<dim3(8, 32, 6), blk, 0, stream>>>(W2,   wt2,  1024, 256, 256, 0);
    boa_kernel<<<6, 384, 0, stream>>>(boff, ba, boa);

    const int mt = (M_N + 127) / 128;   // 316
    for (int i = 0; i < 6; ++i) {
        gemm_bf16<<<dim3(mt, 3), blk, 0, stream>>>(qb, wtoa + (size_t)i * 98304,
                                                   boa + i * 384, oa, M_N, 384, 256, 1);
        gemm_bf16<<<dim3(mt, 2), blk, 0, stream>>>(outb, wtv + (size_t)i * 65536,
                                                   bv + i * 256, value_bf, M_N, 256, 256, 1);
        msda_sample_kernel<<<8 * CHUNK_B, dim3(128), 0, stream>>>(value_bf, oa, refpts, accb);
        gemm_bf16_ln<<<mt, blk, 0, stream>>>(accb, wto + (size_t)i * 65536, bo + i * 256,
                                             out, outb, g1 + i * 256, be1 + i * 256,
                                             nullptr, nullptr, M_N, 256);
        gemm_bf16<<<dim3(mt, 8), blk, 0, stream>>>(outb, wt1 + (size_t)i * 262144,
                                                   b1 + i * 1024, hidden, M_N, 1024, 256, 2);
        gemm_bf16_ln<<<mt, blk, 0, stream>>>(hidden, wt2 + (size_t)i * 262144, b2 + i * 256,
                                             out, outb, g2 + i * 256, be2 + i * 256,
                                             pos, qb, M_N, 1024);
    }
}